// Round 6
// baseline (450.026 us; speedup 1.0000x reference)
//
#include <hip/hip_runtime.h>
#include <hip/hip_bf16.h>

typedef unsigned short u16;
typedef __attribute__((ext_vector_type(8))) short s16x8;   // 8 bf16 MFMA A/B frag
typedef __attribute__((ext_vector_type(4))) float f32x4;   // MFMA C/D frag

#define NN 20000
#define HH 64
#define EMBD 300
#define EE 160000
#define BB 4096
#define NODES 40000

// DIAGNOSTIC (this round only): amplify projm x7 to force it into the top-5
// profile table (top-5 can only show the single slowest kernel; everything
// else hides under the harness's 71-us fill dispatches). Idempotent.
#define PROJM_REP 7

// f32 param block offsets (floats) in workspace (after 16-float header)
#define OFF_PROJB 0
#define OFF_MSGB  64
#define OFF_BIH   192
#define OFF_BHH   576
#define OFF_CW1T  960
#define OFF_CB1   3008
#define OFF_CW2   3024
#define OFF_CB2   3040
#define PARAM_SZ  3072

// bf16 frag-swizzled weight blocks (u16 units). Each "frag" = 512 u16 = one
// 16(row)x32(k) B-tile stored so lane L reads its 8 elements at frag*512+L*8.
#define PB_WIH   0        // 2 l x 24 frags (jt 0..11, kt 0..1)
#define PB_WHH   24576
#define PB_WMT   49152    // 2 l x 8 frags (jt 0..3, kt 0..1)
#define PB_PROJT 57344    // 40 frags (frag = jt*10+kt, jt 0..3, kt 0..9)
#define PB_SZ    77824

// projm LDS A-tile row stride (u16): 344 -> 172 dwords, <=2-way bank alias (free)
#define APAD 344

// zero region: donecnt(1) + pad(15) + ioff(2*(NN+1))
#define ZCNT (16 + 2 * (NN + 1))

__device__ __forceinline__ float b2f(u16 u) {
    union { unsigned int i; float f; } v; v.i = ((unsigned int)u) << 16; return v.f;
}
__device__ __forceinline__ u16 f2b(float f) {
    union { float f; unsigned int u; } v; v.f = f;
    unsigned int u = v.u;
    return (u16)((u + 0x7FFFu + ((u >> 16) & 1u)) >> 16);   // RNE
}
__device__ __forceinline__ float ldf(const void* p, long long i, int isbf) {
    return isbf ? b2f(((const u16*)p)[i]) : ((const float*)p)[i];
}
__device__ __forceinline__ u16 ldb(const void* p, long long i, int isbf) {
    return isbf ? ((const u16*)p)[i] : f2b(((const float*)p)[i]);
}
__device__ __forceinline__ void stf(void* p, long long i, int isbf, float v) {
    if (isbf) ((u16*)p)[i] = f2b(v);
    else      ((float*)p)[i] = v;
}

// in-kernel dtype sniff: wave-uniform, same decision rule as the old sniff
// kernel (64 samples probe[0,2,..,126]; bf16 iff >=48 have exp in [105,127]).
__device__ __forceinline__ int sniff_inline(const u16* probe, int tid)
{
    u16 x = probe[2 * (tid & 63)];
    unsigned int e = (x >> 7) & 0xFF;
    unsigned long long m = __ballot(e >= 105 && e <= 127);
    return (__popcll(m) >= 48) ? 1 : 0;
}

// ---------------- param convert + frag swizzle (+ zeroing, + sniff) ----------
__global__ __launch_bounds__(256) void conv_kernel(
    const void* projW, const void* projb, const void* msgW, const void* msgb,
    const void* wih, const void* whh, const void* bih, const void* bhh,
    const void* cw1, const void* cb1, const void* cw2, const void* cb2,
    float* P, u16* PB, int* zbase)
{
    int tid = threadIdx.x;
    int isbf = sniff_inline((const u16*)projW, tid);
    int i = blockIdx.x * 256 + tid;

    if (i < ZCNT) zbase[i] = 0;    // donecnt + ioff histogram (hist runs after)

    if (i < 64)    P[OFF_PROJB + i] = ldf(projb, i, isbf);
    if (i < 128)   P[OFF_MSGB + i]  = ldf(msgb, i, isbf);
    if (i < 384)   { P[OFF_BIH + i] = ldf(bih, i, isbf); P[OFF_BHH + i] = ldf(bhh, i, isbf); }
    if (i < 2048)  { int t = i >> 7, k = i & 127; P[OFF_CW1T + i] = ldf(cw1, (long long)k * 16 + t, isbf); }
    if (i < 16)    { P[OFF_CB1 + i] = ldf(cb1, i, isbf); P[OFF_CW2 + i] = ldf(cw2, i, isbf); }
    if (i == 0)    P[OFF_CB2] = ldf(cb2, 0, isbf);

    if (i < 24576) {   // Wih/Whh swizzle: per-l 24 frags
        int l = i / 12288, r = i - l * 12288;
        int frag = r >> 9, rr = r & 511, lane = rr >> 3, e = rr & 7;
        int jt = frag >> 1, kt = frag & 1;
        int srow = jt * 16 + (lane & 15);
        int sk = kt * 32 + ((lane >> 4) << 3) + e;
        long long si = (long long)l * 12288 + srow * 64 + sk;
        PB[PB_WIH + i] = ldb(wih, si, isbf);
        PB[PB_WHH + i] = ldb(whh, si, isbf);
    }
    if (i < 8192) {    // msgW^T swizzle
        int l = i >> 12, r = i & 4095;
        int frag = r >> 9, rr = r & 511, lane = rr >> 3, e = rr & 7;
        int jt = frag >> 1, kt = frag & 1;
        int srow = jt * 16 + (lane & 15);
        int sk = kt * 32 + ((lane >> 4) << 3) + e;
        PB[PB_WMT + i] = ldb(msgW, (long long)l * 4096 + sk * 64 + srow, isbf);
    }
    if (i < 20480) {   // projW^T swizzle, k zero-padded >=300
        int frag = i >> 9, rr = i & 511, lane = rr >> 3, e = rr & 7;
        int jt = frag / 10, kt = frag - jt * 10;
        int srow = jt * 16 + (lane & 15);
        int sk = kt * 32 + ((lane >> 4) << 3) + e;
        PB[PB_PROJT + i] = (sk < 300) ? ldb(projW, (long long)sk * 64 + srow, isbf) : (u16)0;
    }
}

// ---------------- CSR build ----------------
__global__ __launch_bounds__(256) void hist_kernel(const int* __restrict__ adj0,
                                                   const int* __restrict__ adj1, int* off)
{
    int e = blockIdx.x * 256 + threadIdx.x;
    if (e >= 2 * EE) return;
    int b = e / EE, le = e - b * EE;
    const int* adj = b ? adj1 : adj0;
    int tgt = adj[2 * le + 1];
    atomicAdd(&off[b * (NN + 1) + tgt + 1], 1);
}

__global__ __launch_bounds__(1024) void scan_kernel(int* off, int* cursor)
{
    int b = blockIdx.x;
    int* o = off + (size_t)b * (NN + 1);
    int* cur = cursor + (size_t)b * NN;
    __shared__ int wsum[16];
    __shared__ int wscan[16];
    int tid = threadIdx.x, wv = tid >> 6, lane = tid & 63;

    // prefetch all 20 chunks: removes 20 global-load round-trips from the
    // serial scan chain (writes below never overlap later reads: write idx
    // < c*1024 < read idx range of chunk c).
    int vpre[20];
    #pragma unroll
    for (int c = 0; c < 20; ++c) {
        int i = c * 1024 + tid;
        vpre[c] = (i < NN) ? o[i + 1] : 0;
    }

    int base = 0;
    #pragma unroll 1
    for (int c = 0; c < 20; ++c) {
        int i = c * 1024 + tid;
        int v = vpre[c];
        int orig = v;
        #pragma unroll
        for (int d = 1; d < 64; d <<= 1) {
            int t = __shfl_up(v, d);
            if (lane >= d) v += t;
        }
        if (lane == 63) wsum[wv] = v;
        __syncthreads();
        if (tid < 16) {
            int w = wsum[tid];
            #pragma unroll
            for (int d = 1; d < 16; d <<= 1) {
                int t = __shfl_up(w, d, 16);
                if (tid >= d) w += t;
            }
            wscan[tid] = w;
        }
        __syncthreads();
        int woff = (wv == 0) ? 0 : wscan[wv - 1];
        int excl = base + woff + v - orig;
        if (i < NN) { o[i] = excl; cur[i] = excl; }
        base += wscan[15];
    }
    if (tid == 0) o[NN] = base;
}

__global__ __launch_bounds__(256) void scatter_kernel(const int* __restrict__ adj0,
                                                      const int* __restrict__ adj1,
                                                      int* cursor, int* esrc)
{
    int e = blockIdx.x * 256 + threadIdx.x;
    if (e >= 2 * EE) return;
    int b = e / EE, le = e - b * EE;
    const int* adj = b ? adj1 : adj0;
    int src = adj[2 * le + 0];
    int tgt = adj[2 * le + 1];
    int pos = atomicAdd(&cursor[b * NN + tgt], 1);
    esrc[(size_t)b * EE + pos] = src;
}

// ---------------- embedding gather + projection (MFMA), flat h output -------
// DIAGNOSTIC: whole body repeated PROJM_REP times (idempotent; staging is
// wave-private so no barrier needed between reps).
__global__ __launch_bounds__(256) void projm_kernel(const void* emb,
                                                    const int* __restrict__ i0,
                                                    const int* __restrict__ i1,
                                                    const float* __restrict__ P,
                                                    const u16* __restrict__ PB,
                                                    u16* __restrict__ h,
                                                    const u16* __restrict__ probe)
{
    __shared__ u16 sA[64 * APAD];
    int tid = threadIdx.x;
    int isbf = sniff_inline(probe, tid);
    int node0 = blockIdx.x * 64;

    #pragma unroll 1
    for (int rep = 0; rep < PROJM_REP; ++rep) {
        // stage 64 embedding rows, 4 threads per row (wave w stages+reads rows 16w..16w+15)
        {
            int r = tid >> 2, sub = tid & 3;
            int n = node0 + r;
            int b = n >= NN;
            int ln = n - b * NN;
            int idx = b ? i1[ln] : i0[ln];
            if (isbf) {
                const ushort4* src = (const ushort4*)((const u16*)emb + (size_t)idx * EMBD);
                ushort4* dst = (ushort4*)(sA + r * APAD);
                for (int c = sub; c < 75; c += 4) dst[c] = src[c];
                if (sub == 0) {
                    ushort4 z = {0, 0, 0, 0};
                    for (int c = 75; c < 80; ++c) dst[c] = z;
                }
            } else {
                // vectorized f32 path: float4 loads (row = 300 f32 = 75 float4)
                const float4* src = (const float4*)((const float*)emb + (size_t)idx * EMBD);
                ushort4* dst = (ushort4*)(sA + r * APAD);
                for (int c = sub; c < 75; c += 4) {
                    float4 f = src[c];
                    ushort4 o4 = { f2b(f.x), f2b(f.y), f2b(f.z), f2b(f.w) };
                    dst[c] = o4;
                }
                if (sub == 0) {
                    ushort4 z = {0, 0, 0, 0};
                    for (int c = 75; c < 80; ++c) dst[c] = z;
                }
            }
        }

        int wv = tid >> 6, lane = tid & 63, quad = lane >> 4, cn = lane & 15;
        int m0 = wv * 16;
        f32x4 acc[4];
        #pragma unroll
        for (int j = 0; j < 4; ++j) {
            float bb = P[OFF_PROJB + j * 16 + cn];
            acc[j] = {bb, bb, bb, bb};
        }
        #pragma unroll
        for (int kt = 0; kt < 10; ++kt) {
            s16x8 a = *(const s16x8*)&sA[(m0 + cn) * APAD + kt * 32 + quad * 8];
            #pragma unroll
            for (int j = 0; j < 4; ++j) {
                s16x8 bfr = *(const s16x8*)&PB[PB_PROJT + (j * 10 + kt) * 512 + lane * 8];
                acc[j] = __builtin_amdgcn_mfma_f32_16x16x32_bf16(a, bfr, acc[j], 0, 0, 0);
            }
        }
        #pragma unroll
        for (int j = 0; j < 4; ++j)
            #pragma unroll
            for (int r = 0; r < 4; ++r)
                h[(size_t)(node0 + m0 + quad * 4 + r) * 64 + j * 16 + cn] = f2b(acc[j][r]);
    }
}

// ---------------- fused gather + GRU step --------------------------------------
// One kernel per propagation step. Block = 32 nodes, 256 threads.
// Grid = 1256 with XCD-branch swizzle: xcd = blockIdx&7 (round-robin dispatch);
// xcds 0-3 handle branch 0, 4-7 branch 1 -> per-XCD gather read-set = one
// branch's h (2.5 MB) + esrc half (0.64 MB): L2-resident (4 MB/XCD).
// Phase A: team of 8 lanes per node gathers full 128-B aligned neighbor rows.
// Phase B: MFMA GRU; epilogue stages in LDS then writes full 128-B rows.
__global__ __launch_bounds__(256) void fstep_kernel(const u16* __restrict__ h_old,
                                                    u16* __restrict__ h_new,
                                                    const int* __restrict__ ioff,
                                                    const int* __restrict__ esrc,
                                                    const float* __restrict__ P,
                                                    const u16* __restrict__ PB, int l)
{
    __shared__ u16 s_S[32 * 64];
    __shared__ u16 s_h[32 * 64];
    __shared__ float s_deg[32];

    int tid = threadIdx.x;
    int bsw = blockIdx.x;
    int half = (bsw >> 2) & 1;                 // (b&7)>>2 : XCD group -> branch
    int t = (bsw >> 3) * 4 + (bsw & 3);        // tile within branch
    if (t >= 625) return;                       // uniform over block
    int node0 = half * NN + t * 32;

    // ---------------- phase A: gather ----------------
    {
        int team = tid >> 3, oct = tid & 7;
        int node = node0 + team;
        int br = node >= NN;
        int ln = node - br * NN;
        const int* o = ioff + (size_t)br * (NN + 1);
        int s0 = o[ln], s1 = o[ln + 1];
        const int* es = esrc + (size_t)br * EE;
        const u16* hb = h_old + (size_t)br * NN * 64;

        // own row + degree first: overlaps the index-load latency below
        *(uint4*)&s_h[team * 64 + oct * 8] =
            *(const uint4*)&h_old[(size_t)node * 64 + oct * 8];
        if (oct == 0) s_deg[team] = (float)(s1 - s0);

        float acc[8];
        #pragma unroll
        for (int k = 0; k < 8; ++k) acc[k] = 0.f;

        int base = s0, rem = s1 - s0;
        while (rem > 0) {
            int cnt = rem < 8 ? rem : 8;
            int myidx = es[base + (oct < cnt ? oct : cnt - 1)];
            #pragma unroll
            for (int j = 0; j < 8; ++j) {
                int e = __shfl(myidx, j, 8);            // dup of last edge when j>=cnt
                uint4 v = *(const uint4*)&hb[(size_t)e * 64 + oct * 8];
                float w = (j < cnt) ? 1.f : 0.f;
                #pragma unroll
                for (int p = 0; p < 4; ++p) {
                    unsigned int u = ((const unsigned int*)&v)[p];
                    union { unsigned int i; float f; } lo, hi;
                    lo.i = u << 16; hi.i = u & 0xffff0000u;
                    acc[2 * p]     += w * lo.f;
                    acc[2 * p + 1] += w * hi.f;
                }
            }
            base += cnt;
            rem -= cnt;
        }

        u16 pk[8];
        #pragma unroll
        for (int k = 0; k < 8; ++k) pk[k] = f2b(acc[k]);
        *(uint4*)&s_S[team * 64 + oct * 8] = *(const uint4*)pk;
    }
    __syncthreads();

    // ---------------- phase B: GRU ----------------
    int wv = tid >> 6, lane = tid & 63;
    int wr = wv >> 1, wc = wv & 1;
    int m0 = wr * 16;
    int quad = lane >> 4, cn = lane & 15;
    int arow = (m0 + cn) * 64 + quad * 8;
    int fl = lane * 8;

    s16x8 aS0 = *(const s16x8*)&s_S[arow];
    s16x8 aS1 = *(const s16x8*)&s_S[arow + 32];
    s16x8 aH0 = *(const s16x8*)&s_h[arow];
    s16x8 aH1 = *(const s16x8*)&s_h[arow + 32];
    __syncthreads();   // all S-frag reads done before inc overwrites s_S

    // phase 1: inc = S @ msgW + deg*msgb  (this wave: cols [wc*32, wc*32+32))
    const u16* WM = PB + PB_WMT + (size_t)l * 4096;
    #pragma unroll
    for (int jtl = 0; jtl < 2; ++jtl) {
        int jt = wc * 2 + jtl;
        float mb = P[OFF_MSGB + l * 64 + jt * 16 + cn];
        f32x4 acc;
        acc[0] = s_deg[m0 + quad * 4 + 0] * mb;
        acc[1] = s_deg[m0 + quad * 4 + 1] * mb;
        acc[2] = s_deg[m0 + quad * 4 + 2] * mb;
        acc[3] = s_deg[m0 + quad * 4 + 3] * mb;
        acc = __builtin_amdgcn_mfma_f32_16x16x32_bf16(aS0, *(const s16x8*)&WM[(jt * 2 + 0) * 512 + fl], acc, 0, 0, 0);
        acc = __builtin_amdgcn_mfma_f32_16x16x32_bf16(aS1, *(const s16x8*)&WM[(jt * 2 + 1) * 512 + fl], acc, 0, 0, 0);
        #pragma unroll
        for (int r = 0; r < 4; ++r)
            s_S[(m0 + quad * 4 + r) * 64 + jt * 16 + cn] = f2b(acc[r]);
    }
    __syncthreads();   // full inc rows ready

    s16x8 aI0 = *(const s16x8*)&s_S[arow];
    s16x8 aI1 = *(const s16x8*)&s_S[arow + 32];
    __syncthreads();   // aI frag reads done before epilogue re-writes s_S

    const u16* WI = PB + PB_WIH + (size_t)l * 12288;
    const u16* WH = PB + PB_WHH + (size_t)l * 12288;
    const float* bi = P + OFF_BIH + l * 192;
    const float* bh = P + OFF_BHH + l * 192;

    #pragma unroll
    for (int cl = 0; cl < 2; ++cl) {
        int jt = wc * 2 + cl;
        int j0 = jt * 16;
        float vr = bi[j0 + cn], vz = bi[64 + j0 + cn], vn = bi[128 + j0 + cn];
        float wr_ = bh[j0 + cn], wz = bh[64 + j0 + cn], wn = bh[128 + j0 + cn];
        f32x4 gr = {vr, vr, vr, vr}, gz = {vz, vz, vz, vz}, gn = {vn, vn, vn, vn};
        f32x4 hr = {wr_, wr_, wr_, wr_}, hz = {wz, wz, wz, wz}, hn = {wn, wn, wn, wn};
        int fr = (jt * 2) * 512 + fl, frz = ((4 + jt) * 2) * 512 + fl, frn = ((8 + jt) * 2) * 512 + fl;
        gr = __builtin_amdgcn_mfma_f32_16x16x32_bf16(aI0, *(const s16x8*)&WI[fr], gr, 0, 0, 0);
        gr = __builtin_amdgcn_mfma_f32_16x16x32_bf16(aI1, *(const s16x8*)&WI[fr + 512], gr, 0, 0, 0);
        gz = __builtin_amdgcn_mfma_f32_16x16x32_bf16(aI0, *(const s16x8*)&WI[frz], gz, 0, 0, 0);
        gz = __builtin_amdgcn_mfma_f32_16x16x32_bf16(aI1, *(const s16x8*)&WI[frz + 512], gz, 0, 0, 0);
        gn = __builtin_amdgcn_mfma_f32_16x16x32_bf16(aI0, *(const s16x8*)&WI[frn], gn, 0, 0, 0);
        gn = __builtin_amdgcn_mfma_f32_16x16x32_bf16(aI1, *(const s16x8*)&WI[frn + 512], gn, 0, 0, 0);
        hr = __builtin_amdgcn_mfma_f32_16x16x32_bf16(aH0, *(const s16x8*)&WH[fr], hr, 0, 0, 0);
        hr = __builtin_amdgcn_mfma_f32_16x16x32_bf16(aH1, *(const s16x8*)&WH[fr + 512], hr, 0, 0, 0);
        hz = __builtin_amdgcn_mfma_f32_16x16x32_bf16(aH0, *(const s16x8*)&WH[frz], hz, 0, 0, 0);
        hz = __builtin_amdgcn_mfma_f32_16x16x32_bf16(aH1, *(const s16x8*)&WH[frz + 512], hz, 0, 0, 0);
        hn = __builtin_amdgcn_mfma_f32_16x16x32_bf16(aH0, *(const s16x8*)&WH[frn], hn, 0, 0, 0);
        hn = __builtin_amdgcn_mfma_f32_16x16x32_bf16(aH1, *(const s16x8*)&WH[frn + 512], hn, 0, 0, 0);
        #pragma unroll
        for (int r = 0; r < 4; ++r) {
            int row = m0 + quad * 4 + r;
            float rr = 1.f / (1.f + __expf(-(gr[r] + hr[r])));
            float zz = 1.f / (1.f + __expf(-(gz[r] + hz[r])));
            float nn = tanhf(gn[r] + rr * hn[r]);
            float ho = b2f(s_h[row * 64 + j0 + cn]);
            s_S[row * 64 + j0 + cn] = f2b((1.f - zz) * nn + zz * ho);
        }
    }
    __syncthreads();   // all result tiles staged in s_S

    // vectorized epilogue: full 128-B row stores (8 lanes x 16 B per node row)
    {
        int team = tid >> 3, oct = tid & 7;
        int node = node0 + team;
        *(uint4*)&h_new[(size_t)node * 64 + oct * 8] =
            *(const uint4*)&s_S[team * 64 + oct * 8];
    }
}

// ---------------- classifier: wave-per-sample (flat h reads) ------------------
// (loss re-split into its own kernel: the fused last-block pattern needs
// device-scope __threadfence = cross-XCD L2 writeback per block -> measured
// 84.7 us @ 2.3% VALUBusy in R5. Kernel boundary is the cheap barrier.)
__global__ __launch_bounds__(256) void cls_kernel(const u16* __restrict__ h,
                                                  const int* __restrict__ p0,
                                                  const int* __restrict__ p1,
                                                  const int* __restrict__ labels,
                                                  const float* __restrict__ P,
                                                  void* out, float* partial,
                                                  const u16* __restrict__ probe)
{
    int tid = threadIdx.x;
    int isbf = sniff_inline(probe, tid);
    int wv = tid >> 6, lane = tid & 63;
    int s = blockIdx.x * 4 + wv;               // 1024 blocks x 4 waves = 4096
    int n0 = p0[s], n1 = p1[s];
    float f0 = b2f(h[(size_t)n0 * 64 + lane]);
    float f1 = b2f(h[(size_t)(NN + n1) * 64 + lane]);
    float z = P[OFF_CB2];
    #pragma unroll
    for (int t = 0; t < 16; ++t) {
        float part = f0 * P[OFF_CW1T + t * 128 + lane] + f1 * P[OFF_CW1T + t * 128 + 64 + lane];
        #pragma unroll
        for (int off = 32; off; off >>= 1) part += __shfl_xor(part, off);
        z += fmaxf(part + P[OFF_CB1 + t], 0.f) * P[OFF_CW2 + t];
    }
    float p = 1.f / (1.f + expf(-z));
    float y = (float)labels[s];
    const float eps = 1e-7f;
    float pc  = fminf(fmaxf(p, eps), 1.f);
    float pc1 = fminf(fmaxf(1.f - p, eps), 1.f);
    float term = y * logf(pc) + (1.f - y) * logf(pc1);
    __shared__ float red[4];
    if (lane == 0) { stf(out, s, isbf, p); red[wv] = term; }
    __syncthreads();
    if (tid == 0) partial[blockIdx.x] = red[0] + red[1] + red[2] + red[3];
}

__global__ __launch_bounds__(256) void loss_kernel(const float* __restrict__ partial,
                                                   void* out, const u16* __restrict__ probe)
{
    int tid = threadIdx.x;
    int isbf = sniff_inline(probe, tid);
    __shared__ float red[256];
    float s = 0.f;
    for (int i = tid; i < 1024; i += 256) s += partial[i];
    red[tid] = s;
    __syncthreads();
    for (int d = 128; d > 0; d >>= 1) {
        if (tid < d) red[tid] += red[tid + d];
        __syncthreads();
    }
    if (tid == 0) stf(out, BB, isbf, -red[0] / (float)BB);
}

extern "C" void kernel_launch(void* const* d_in, const int* in_sizes, int n_in,
                              void* d_out, int out_size, void* d_ws, size_t ws_size,
                              hipStream_t stream)
{
    const int* adj0   = (const int*)d_in[2];
    const int* adj1   = (const int*)d_in[3];
    const int* prop0  = (const int*)d_in[4];
    const int* prop1  = (const int*)d_in[5];
    const int* labels = (const int*)d_in[6];
    const u16* probe  = (const u16*)d_in[8];   // proj_W doubles as dtype probe

    float* P  = (float*)d_ws + 16;
    u16* PB   = (u16*)(P + PARAM_SZ);
    // h rows are 128 B; align h0 to 256 B so every row is exactly one cache line
    u16* h0   = (u16*)(((uintptr_t)(PB + PB_SZ) + 255) & ~(uintptr_t)255);
    u16* h1   = h0 + (size_t)NODES * 64;
    float* partial = (float*)(h1 + (size_t)NODES * 64);
    int* zbase  = (int*)(partial + 1024);      // [donecnt(1), pad(15), ioff(40002)]
    int* ioff   = zbase + 16;
    int* cursor = ioff + 2 * (NN + 1) + 62;
    int* esrc   = cursor + 2 * NN;

    // conv also zeroes donecnt+ioff (runs before hist in stream order) and
    // sniffs dtype inline -> no memset node, no sniff node.
    conv_kernel<<<157, 256, 0, stream>>>(d_in[8], d_in[9], d_in[10], d_in[11], d_in[12], d_in[13],
                                         d_in[14], d_in[15], d_in[16], d_in[17], d_in[18], d_in[19],
                                         P, PB, zbase);
    hist_kernel<<<(2 * EE) / 256, 256, 0, stream>>>(adj0, adj1, ioff);
    scan_kernel<<<2, 1024, 0, stream>>>(ioff, cursor);
    scatter_kernel<<<(2 * EE) / 256, 256, 0, stream>>>(adj0, adj1, cursor, esrc);
    projm_kernel<<<(2 * NN) / 64, 256, 0, stream>>>(d_in[7], (const int*)d_in[0],
                                                    (const int*)d_in[1], P, PB, h0, probe);

    u16* hcur = h0;
    u16* hnext = h1;
    for (int l = 0; l < 2; ++l) {
        for (int t = 0; t < 3; ++t) {
            fstep_kernel<<<1256, 256, 0, stream>>>(hcur, hnext, ioff, esrc, P, PB, l);
            u16* tmp = hcur; hcur = hnext; hnext = tmp;
        }
    }
    // 6 steps -> final state back in h0 (== hcur)

    cls_kernel<<<BB / 4, 256, 0, stream>>>(hcur, prop0, prop1, labels, P, d_out,
                                           partial, probe);
    loss_kernel<<<1, 256, 0, stream>>>(partial, d_out, probe);
}

// Round 7
// 386.285 us; speedup vs baseline: 1.1650x; 1.1650x over previous
//
#include <hip/hip_runtime.h>
#include <hip/hip_bf16.h>

typedef unsigned short u16;
typedef __attribute__((ext_vector_type(8))) short s16x8;   // 8 bf16 MFMA A/B frag
typedef __attribute__((ext_vector_type(4))) float f32x4;   // MFMA C/D frag

#define NN 20000
#define HH 64
#define EMBD 300
#define EE 160000
#define BB 4096
#define NODES 40000

// f32 param block offsets (floats) in workspace (after 16-float header)
#define OFF_PROJB 0
#define OFF_MSGB  64
#define OFF_BIH   192
#define OFF_BHH   576
#define OFF_CW1T  960
#define OFF_CB1   3008
#define OFF_CW2   3024
#define OFF_CB2   3040
#define PARAM_SZ  3072

// bf16 frag-swizzled weight blocks (u16 units). Each "frag" = 512 u16 = one
// 16(row)x32(k) B-tile stored so lane L reads its 8 elements at frag*512+L*8.
#define PB_WIH   0        // 2 l x 24 frags (jt 0..11, kt 0..1)
#define PB_WHH   24576
#define PB_WMT   49152    // 2 l x 8 frags (jt 0..3, kt 0..1)
#define PB_PROJT 57344    // 40 frags (frag = jt*10+kt, jt 0..3, kt 0..9)
#define PB_SZ    77824

// projm LDS A-tile row stride (u16): 344 -> 172 dwords, <=2-way bank alias (free)
#define APAD 344

// zero region: donecnt(1) + pad(15) + ioff(2*(NN+1))
#define ZCNT (16 + 2 * (NN + 1))

__device__ __forceinline__ float b2f(u16 u) {
    union { unsigned int i; float f; } v; v.i = ((unsigned int)u) << 16; return v.f;
}
__device__ __forceinline__ u16 f2b(float f) {
    union { float f; unsigned int u; } v; v.f = f;
    unsigned int u = v.u;
    return (u16)((u + 0x7FFFu + ((u >> 16) & 1u)) >> 16);   // RNE
}
__device__ __forceinline__ float ldf(const void* p, long long i, int isbf) {
    return isbf ? b2f(((const u16*)p)[i]) : ((const float*)p)[i];
}
__device__ __forceinline__ u16 ldb(const void* p, long long i, int isbf) {
    return isbf ? ((const u16*)p)[i] : f2b(((const float*)p)[i]);
}
__device__ __forceinline__ void stf(void* p, long long i, int isbf, float v) {
    if (isbf) ((u16*)p)[i] = f2b(v);
    else      ((float*)p)[i] = v;
}

// in-kernel dtype sniff: wave-uniform, same decision rule as the old sniff
// kernel (64 samples probe[0,2,..,126]; bf16 iff >=48 have exp in [105,127]).
__device__ __forceinline__ int sniff_inline(const u16* probe, int tid)
{
    u16 x = probe[2 * (tid & 63)];
    unsigned int e = (x >> 7) & 0xFF;
    unsigned long long m = __ballot(e >= 105 && e <= 127);
    return (__popcll(m) >= 48) ? 1 : 0;
}

// ---------------- param convert + frag swizzle (+ zeroing, + sniff) ----------
__global__ __launch_bounds__(256) void conv_kernel(
    const void* projW, const void* projb, const void* msgW, const void* msgb,
    const void* wih, const void* whh, const void* bih, const void* bhh,
    const void* cw1, const void* cb1, const void* cw2, const void* cb2,
    float* P, u16* PB, int* zbase)
{
    int tid = threadIdx.x;
    int isbf = sniff_inline((const u16*)projW, tid);
    int i = blockIdx.x * 256 + tid;

    if (i < ZCNT) zbase[i] = 0;    // donecnt + ioff histogram (hist runs after)

    if (i < 64)    P[OFF_PROJB + i] = ldf(projb, i, isbf);
    if (i < 128)   P[OFF_MSGB + i]  = ldf(msgb, i, isbf);
    if (i < 384)   { P[OFF_BIH + i] = ldf(bih, i, isbf); P[OFF_BHH + i] = ldf(bhh, i, isbf); }
    if (i < 2048)  { int t = i >> 7, k = i & 127; P[OFF_CW1T + i] = ldf(cw1, (long long)k * 16 + t, isbf); }
    if (i < 16)    { P[OFF_CB1 + i] = ldf(cb1, i, isbf); P[OFF_CW2 + i] = ldf(cw2, i, isbf); }
    if (i == 0)    P[OFF_CB2] = ldf(cb2, 0, isbf);

    if (i < 24576) {   // Wih/Whh swizzle: per-l 24 frags
        int l = i / 12288, r = i - l * 12288;
        int frag = r >> 9, rr = r & 511, lane = rr >> 3, e = rr & 7;
        int jt = frag >> 1, kt = frag & 1;
        int srow = jt * 16 + (lane & 15);
        int sk = kt * 32 + ((lane >> 4) << 3) + e;
        long long si = (long long)l * 12288 + srow * 64 + sk;
        PB[PB_WIH + i] = ldb(wih, si, isbf);
        PB[PB_WHH + i] = ldb(whh, si, isbf);
    }
    if (i < 8192) {    // msgW^T swizzle
        int l = i >> 12, r = i & 4095;
        int frag = r >> 9, rr = r & 511, lane = rr >> 3, e = rr & 7;
        int jt = frag >> 1, kt = frag & 1;
        int srow = jt * 16 + (lane & 15);
        int sk = kt * 32 + ((lane >> 4) << 3) + e;
        PB[PB_WMT + i] = ldb(msgW, (long long)l * 4096 + sk * 64 + srow, isbf);
    }
    if (i < 20480) {   // projW^T swizzle, k zero-padded >=300
        int frag = i >> 9, rr = i & 511, lane = rr >> 3, e = rr & 7;
        int jt = frag / 10, kt = frag - jt * 10;
        int srow = jt * 16 + (lane & 15);
        int sk = kt * 32 + ((lane >> 4) << 3) + e;
        PB[PB_PROJT + i] = (sk < 300) ? ldb(projW, (long long)sk * 64 + srow, isbf) : (u16)0;
    }
}

// ---------------- CSR build ----------------
__global__ __launch_bounds__(256) void hist_kernel(const int* __restrict__ adj0,
                                                   const int* __restrict__ adj1, int* off)
{
    int e = blockIdx.x * 256 + threadIdx.x;
    if (e >= 2 * EE) return;
    int b = e / EE, le = e - b * EE;
    const int* adj = b ? adj1 : adj0;
    int tgt = adj[2 * le + 1];
    atomicAdd(&off[b * (NN + 1) + tgt + 1], 1);
}

// scan v2: per-thread contiguous 20-element segment (coalesced loads), local
// register scan, one wave-scan + one 16-wide scan -> 2 block barriers total
// (old chunk-serial version had 40 barriers on the critical path).
__global__ __launch_bounds__(1024) void scan_kernel(int* off, int* cursor)
{
    int b = blockIdx.x;
    int* o = off + (size_t)b * (NN + 1);
    int* cur = cursor + (size_t)b * NN;
    __shared__ int wsum[16];
    __shared__ int woff_s[16];
    int tid = threadIdx.x, wv = tid >> 6, lane = tid & 63;

    int base = tid * 20;
    int v[20];                 // local inclusive prefix
    int tot = 0;
    #pragma unroll
    for (int k = 0; k < 20; ++k) {
        int i = base + k;
        int x = (i < NN) ? o[i + 1] : 0;
        tot += x;
        v[k] = tot;
    }
    // wave inclusive scan of per-thread totals
    int incl = tot;
    #pragma unroll
    for (int d = 1; d < 64; d <<= 1) {
        int t = __shfl_up(incl, d);
        if (lane >= d) incl += t;
    }
    if (lane == 63) wsum[wv] = incl;
    int lane_excl = incl - tot;
    __syncthreads();           // also orders: all o[] reads before writes below
    if (tid < 16) {
        int w = wsum[tid];
        int s = w;
        #pragma unroll
        for (int d = 1; d < 16; d <<= 1) {
            int t = __shfl_up(s, d, 16);
            if (tid >= d) s += t;
        }
        woff_s[tid] = s - w;   // exclusive wave offset
    }
    __syncthreads();
    int pexcl = woff_s[wv] + lane_excl;
    int run = pexcl;
    #pragma unroll
    for (int k = 0; k < 20; ++k) {
        int i = base + k;
        if (i < NN) { o[i] = run; cur[i] = run; }
        run = pexcl + v[k];
    }
    if (tid == 1023) o[NN] = pexcl;   // base>=NN -> pexcl == grand total
}

__global__ __launch_bounds__(256) void scatter_kernel(const int* __restrict__ adj0,
                                                      const int* __restrict__ adj1,
                                                      int* cursor, int* esrc)
{
    int e = blockIdx.x * 256 + threadIdx.x;
    if (e >= 2 * EE) return;
    int b = e / EE, le = e - b * EE;
    const int* adj = b ? adj1 : adj0;
    int src = adj[2 * le + 0];
    int tgt = adj[2 * le + 1];
    int pos = atomicAdd(&cursor[b * NN + tgt], 1);
    esrc[(size_t)b * EE + pos] = src;
}

// ---------------- embedding gather + projection (MFMA), flat h output -------
// Staging: 8 lanes/row (wave-private rows), uint4 chunks when the 600-B row is
// 16-B aligned (even idx) -> 38 requests/row in 128-B coalesced runs; uint2
// fallback otherwise. (R6 probe: projm was request/latency-bound at 15 us.)
__global__ __launch_bounds__(256) void projm_kernel(const void* emb,
                                                    const int* __restrict__ i0,
                                                    const int* __restrict__ i1,
                                                    const float* __restrict__ P,
                                                    const u16* __restrict__ PB,
                                                    u16* __restrict__ h,
                                                    const u16* __restrict__ probe)
{
    __shared__ u16 sA[64 * APAD];
    int tid = threadIdx.x;
    int isbf = sniff_inline(probe, tid);
    int node0 = blockIdx.x * 64;
    int wv = tid >> 6, lane = tid & 63;

    {
        int oct = lane & 7;
        int rbase = wv * 16 + (lane >> 3);     // wave-private rows
        #pragma unroll
        for (int rr = 0; rr < 2; ++rr) {
            int r = rbase + rr * 8;
            int n = node0 + r;
            int bb2 = n >= NN;
            int ln = n - bb2 * NN;
            int idx = bb2 ? i1[ln] : i0[ln];
            u16* dst = sA + r * APAD;
            if (isbf) {
                const u16* src = (const u16*)emb + (size_t)idx * EMBD;
                if ((idx & 1) == 0) {
                    // 16-B aligned row: 37 x uint4 + 8-B tail
                    for (int c = oct; c < 37; c += 8)
                        *(uint4*)(dst + c * 8) = *(const uint4*)(src + c * 8);
                    if (oct == 7)
                        *(uint2*)(dst + 296) = *(const uint2*)(src + 296);
                } else {
                    // 8-B aligned row: 75 x uint2
                    for (int c = oct; c < 75; c += 8)
                        *(uint2*)(dst + c * 4) = *(const uint2*)(src + c * 4);
                }
                if (oct == 0) {
                    ushort4 z = {0, 0, 0, 0};
                    ushort4* d4 = (ushort4*)dst;
                    #pragma unroll
                    for (int c = 75; c < 80; ++c) d4[c] = z;
                }
            } else {
                // f32 path: 75 x float4 (16-B aligned: 1200-B rows)
                const float4* src = (const float4*)((const float*)emb + (size_t)idx * EMBD);
                for (int c = oct; c < 75; c += 8) {
                    float4 f = src[c];
                    ushort4 o4 = { f2b(f.x), f2b(f.y), f2b(f.z), f2b(f.w) };
                    *(ushort4*)(dst + c * 4) = o4;
                }
                if (oct == 0) {
                    ushort4 z = {0, 0, 0, 0};
                    ushort4* d4 = (ushort4*)dst;
                    #pragma unroll
                    for (int c = 75; c < 80; ++c) d4[c] = z;
                }
            }
        }
    }

    int quad = lane >> 4, cn = lane & 15;
    int m0 = wv * 16;
    f32x4 acc[4];
    #pragma unroll
    for (int j = 0; j < 4; ++j) {
        float bb = P[OFF_PROJB + j * 16 + cn];
        acc[j] = {bb, bb, bb, bb};
    }
    #pragma unroll
    for (int kt = 0; kt < 10; ++kt) {
        s16x8 a = *(const s16x8*)&sA[(m0 + cn) * APAD + kt * 32 + quad * 8];
        #pragma unroll
        for (int j = 0; j < 4; ++j) {
            s16x8 bfr = *(const s16x8*)&PB[PB_PROJT + (j * 10 + kt) * 512 + lane * 8];
            acc[j] = __builtin_amdgcn_mfma_f32_16x16x32_bf16(a, bfr, acc[j], 0, 0, 0);
        }
    }
    #pragma unroll
    for (int j = 0; j < 4; ++j)
        #pragma unroll
        for (int r = 0; r < 4; ++r)
            h[(size_t)(node0 + m0 + quad * 4 + r) * 64 + j * 16 + cn] = f2b(acc[j][r]);
}

// ---------------- fused gather + GRU step --------------------------------------
// One kernel per propagation step. Block = 32 nodes, 256 threads.
// Grid = 1256 with XCD-branch swizzle (xcds 0-3 branch 0, 4-7 branch 1:
// per-XCD gather read-set L2-resident).
// Phase A: team of 8 lanes per node gathers full 128-B aligned neighbor rows.
// Phase B: MFMA GRU. inc goes to a separate s_inc buffer -> only 3 block
// barriers per step (was 5: the two overwrite-hazard barriers are gone).
__global__ __launch_bounds__(256) void fstep_kernel(const u16* __restrict__ h_old,
                                                    u16* __restrict__ h_new,
                                                    const int* __restrict__ ioff,
                                                    const int* __restrict__ esrc,
                                                    const float* __restrict__ P,
                                                    const u16* __restrict__ PB, int l)
{
    __shared__ u16 s_S[32 * 64];
    __shared__ u16 s_h[32 * 64];
    __shared__ u16 s_inc[32 * 64];
    __shared__ float s_deg[32];

    int tid = threadIdx.x;
    int bsw = blockIdx.x;
    int half = (bsw >> 2) & 1;                 // (b&7)>>2 : XCD group -> branch
    int t = (bsw >> 3) * 4 + (bsw & 3);        // tile within branch
    if (t >= 625) return;                       // uniform over block
    int node0 = half * NN + t * 32;

    // ---------------- phase A: gather ----------------
    {
        int team = tid >> 3, oct = tid & 7;
        int node = node0 + team;
        int br = node >= NN;
        int ln = node - br * NN;
        const int* o = ioff + (size_t)br * (NN + 1);
        int s0 = o[ln], s1 = o[ln + 1];
        const int* es = esrc + (size_t)br * EE;
        const u16* hb = h_old + (size_t)br * NN * 64;

        // own row + degree first: overlaps the index-load latency below
        *(uint4*)&s_h[team * 64 + oct * 8] =
            *(const uint4*)&h_old[(size_t)node * 64 + oct * 8];
        if (oct == 0) s_deg[team] = (float)(s1 - s0);

        float acc[8];
        #pragma unroll
        for (int k = 0; k < 8; ++k) acc[k] = 0.f;

        int base = s0, rem = s1 - s0;
        while (rem > 0) {
            int cnt = rem < 8 ? rem : 8;
            int myidx = es[base + (oct < cnt ? oct : cnt - 1)];
            #pragma unroll
            for (int j = 0; j < 8; ++j) {
                int e = __shfl(myidx, j, 8);            // dup of last edge when j>=cnt
                uint4 v = *(const uint4*)&hb[(size_t)e * 64 + oct * 8];
                float w = (j < cnt) ? 1.f : 0.f;
                #pragma unroll
                for (int p = 0; p < 4; ++p) {
                    unsigned int u = ((const unsigned int*)&v)[p];
                    union { unsigned int i; float f; } lo, hi;
                    lo.i = u << 16; hi.i = u & 0xffff0000u;
                    acc[2 * p]     += w * lo.f;
                    acc[2 * p + 1] += w * hi.f;
                }
            }
            base += cnt;
            rem -= cnt;
        }

        u16 pk[8];
        #pragma unroll
        for (int k = 0; k < 8; ++k) pk[k] = f2b(acc[k]);
        *(uint4*)&s_S[team * 64 + oct * 8] = *(const uint4*)pk;
    }
    __syncthreads();   // (1) S/h/deg staged

    // ---------------- phase B: GRU ----------------
    int wv = tid >> 6, lane = tid & 63;
    int wr = wv >> 1, wc = wv & 1;
    int m0 = wr * 16;
    int quad = lane >> 4, cn = lane & 15;
    int arow = (m0 + cn) * 64 + quad * 8;
    int fl = lane * 8;

    s16x8 aS0 = *(const s16x8*)&s_S[arow];
    s16x8 aS1 = *(const s16x8*)&s_S[arow + 32];
    s16x8 aH0 = *(const s16x8*)&s_h[arow];
    s16x8 aH1 = *(const s16x8*)&s_h[arow + 32];

    // phase 1: inc = S @ msgW + deg*msgb -> s_inc (no overwrite hazard)
    const u16* WM = PB + PB_WMT + (size_t)l * 4096;
    #pragma unroll
    for (int jtl = 0; jtl < 2; ++jtl) {
        int jt = wc * 2 + jtl;
        float mb = P[OFF_MSGB + l * 64 + jt * 16 + cn];
        f32x4 acc;
        acc[0] = s_deg[m0 + quad * 4 + 0] * mb;
        acc[1] = s_deg[m0 + quad * 4 + 1] * mb;
        acc[2] = s_deg[m0 + quad * 4 + 2] * mb;
        acc[3] = s_deg[m0 + quad * 4 + 3] * mb;
        acc = __builtin_amdgcn_mfma_f32_16x16x32_bf16(aS0, *(const s16x8*)&WM[(jt * 2 + 0) * 512 + fl], acc, 0, 0, 0);
        acc = __builtin_amdgcn_mfma_f32_16x16x32_bf16(aS1, *(const s16x8*)&WM[(jt * 2 + 1) * 512 + fl], acc, 0, 0, 0);
        #pragma unroll
        for (int r = 0; r < 4; ++r)
            s_inc[(m0 + quad * 4 + r) * 64 + jt * 16 + cn] = f2b(acc[r]);
    }
    __syncthreads();   // (2) full inc rows ready

    s16x8 aI0 = *(const s16x8*)&s_inc[arow];
    s16x8 aI1 = *(const s16x8*)&s_inc[arow + 32];
    const u16* WI = PB + PB_WIH + (size_t)l * 12288;
    const u16* WH = PB + PB_WHH + (size_t)l * 12288;
    const float* bi = P + OFF_BIH + l * 192;
    const float* bh = P + OFF_BHH + l * 192;

    #pragma unroll
    for (int cl = 0; cl < 2; ++cl) {
        int jt = wc * 2 + cl;
        int j0 = jt * 16;
        float vr = bi[j0 + cn], vz = bi[64 + j0 + cn], vn = bi[128 + j0 + cn];
        float wr_ = bh[j0 + cn], wz = bh[64 + j0 + cn], wn = bh[128 + j0 + cn];
        f32x4 gr = {vr, vr, vr, vr}, gz = {vz, vz, vz, vz}, gn = {vn, vn, vn, vn};
        f32x4 hr = {wr_, wr_, wr_, wr_}, hz = {wz, wz, wz, wz}, hn = {wn, wn, wn, wn};
        int fr = (jt * 2) * 512 + fl, frz = ((4 + jt) * 2) * 512 + fl, frn = ((8 + jt) * 2) * 512 + fl;
        gr = __builtin_amdgcn_mfma_f32_16x16x32_bf16(aI0, *(const s16x8*)&WI[fr], gr, 0, 0, 0);
        gr = __builtin_amdgcn_mfma_f32_16x16x32_bf16(aI1, *(const s16x8*)&WI[fr + 512], gr, 0, 0, 0);
        gz = __builtin_amdgcn_mfma_f32_16x16x32_bf16(aI0, *(const s16x8*)&WI[frz], gz, 0, 0, 0);
        gz = __builtin_amdgcn_mfma_f32_16x16x32_bf16(aI1, *(const s16x8*)&WI[frz + 512], gz, 0, 0, 0);
        gn = __builtin_amdgcn_mfma_f32_16x16x32_bf16(aI0, *(const s16x8*)&WI[frn], gn, 0, 0, 0);
        gn = __builtin_amdgcn_mfma_f32_16x16x32_bf16(aI1, *(const s16x8*)&WI[frn + 512], gn, 0, 0, 0);
        hr = __builtin_amdgcn_mfma_f32_16x16x32_bf16(aH0, *(const s16x8*)&WH[fr], hr, 0, 0, 0);
        hr = __builtin_amdgcn_mfma_f32_16x16x32_bf16(aH1, *(const s16x8*)&WH[fr + 512], hr, 0, 0, 0);
        hz = __builtin_amdgcn_mfma_f32_16x16x32_bf16(aH0, *(const s16x8*)&WH[frz], hz, 0, 0, 0);
        hz = __builtin_amdgcn_mfma_f32_16x16x32_bf16(aH1, *(const s16x8*)&WH[frz + 512], hz, 0, 0, 0);
        hn = __builtin_amdgcn_mfma_f32_16x16x32_bf16(aH0, *(const s16x8*)&WH[frn], hn, 0, 0, 0);
        hn = __builtin_amdgcn_mfma_f32_16x16x32_bf16(aH1, *(const s16x8*)&WH[frn + 512], hn, 0, 0, 0);
        #pragma unroll
        for (int r = 0; r < 4; ++r) {
            int row = m0 + quad * 4 + r;
            float rr = 1.f / (1.f + __expf(-(gr[r] + hr[r])));
            float zz = 1.f / (1.f + __expf(-(gz[r] + hz[r])));
            float nn = tanhf(gn[r] + rr * hn[r]);
            float ho = b2f(s_h[row * 64 + j0 + cn]);
            s_S[row * 64 + j0 + cn] = f2b((1.f - zz) * nn + zz * ho);   // s_S dead after (1)->frags
        }
    }
    __syncthreads();   // (3) all result tiles staged in s_S

    // vectorized epilogue: full 128-B row stores (8 lanes x 16 B per node row)
    {
        int team = tid >> 3, oct = tid & 7;
        int node = node0 + team;
        *(uint4*)&h_new[(size_t)node * 64 + oct * 8] =
            *(const uint4*)&s_S[team * 64 + oct * 8];
    }
}

// ---------------- classifier: wave-per-sample (flat h reads) ------------------
// (loss stays a separate kernel: fused last-block reduce needs device-scope
// __threadfence = cross-XCD writeback per block -> measured 84.7 us in R5.)
__global__ __launch_bounds__(256) void cls_kernel(const u16* __restrict__ h,
                                                  const int* __restrict__ p0,
                                                  const int* __restrict__ p1,
                                                  const int* __restrict__ labels,
                                                  const float* __restrict__ P,
                                                  void* out, float* partial,
                                                  const u16* __restrict__ probe)
{
    int tid = threadIdx.x;
    int isbf = sniff_inline(probe, tid);
    int wv = tid >> 6, lane = tid & 63;
    int s = blockIdx.x * 4 + wv;               // 1024 blocks x 4 waves = 4096
    int n0 = p0[s], n1 = p1[s];
    float f0 = b2f(h[(size_t)n0 * 64 + lane]);
    float f1 = b2f(h[(size_t)(NN + n1) * 64 + lane]);
    float z = P[OFF_CB2];
    #pragma unroll
    for (int t = 0; t < 16; ++t) {
        float part = f0 * P[OFF_CW1T + t * 128 + lane] + f1 * P[OFF_CW1T + t * 128 + 64 + lane];
        #pragma unroll
        for (int off = 32; off; off >>= 1) part += __shfl_xor(part, off);
        z += fmaxf(part + P[OFF_CB1 + t], 0.f) * P[OFF_CW2 + t];
    }
    float p = 1.f / (1.f + expf(-z));
    float y = (float)labels[s];
    const float eps = 1e-7f;
    float pc  = fminf(fmaxf(p, eps), 1.f);
    float pc1 = fminf(fmaxf(1.f - p, eps), 1.f);
    float term = y * logf(pc) + (1.f - y) * logf(pc1);
    __shared__ float red[4];
    if (lane == 0) { stf(out, s, isbf, p); red[wv] = term; }
    __syncthreads();
    if (tid == 0) partial[blockIdx.x] = red[0] + red[1] + red[2] + red[3];
}

__global__ __launch_bounds__(256) void loss_kernel(const float* __restrict__ partial,
                                                   void* out, const u16* __restrict__ probe)
{
    int tid = threadIdx.x;
    int isbf = sniff_inline(probe, tid);
    __shared__ float red[256];
    float s = 0.f;
    for (int i = tid; i < 1024; i += 256) s += partial[i];
    red[tid] = s;
    __syncthreads();
    for (int d = 128; d > 0; d >>= 1) {
        if (tid < d) red[tid] += red[tid + d];
        __syncthreads();
    }
    if (tid == 0) stf(out, BB, isbf, -red[0] / (float)BB);
}

extern "C" void kernel_launch(void* const* d_in, const int* in_sizes, int n_in,
                              void* d_out, int out_size, void* d_ws, size_t ws_size,
                              hipStream_t stream)
{
    const int* adj0   = (const int*)d_in[2];
    const int* adj1   = (const int*)d_in[3];
    const int* prop0  = (const int*)d_in[4];
    const int* prop1  = (const int*)d_in[5];
    const int* labels = (const int*)d_in[6];
    const u16* probe  = (const u16*)d_in[8];   // proj_W doubles as dtype probe

    float* P  = (float*)d_ws + 16;
    u16* PB   = (u16*)(P + PARAM_SZ);
    // h rows are 128 B; align h0 to 256 B so every row is exactly one cache line
    u16* h0   = (u16*)(((uintptr_t)(PB + PB_SZ) + 255) & ~(uintptr_t)255);
    u16* h1   = h0 + (size_t)NODES * 64;
    float* partial = (float*)(h1 + (size_t)NODES * 64);
    int* zbase  = (int*)(partial + 1024);      // [donecnt(1), pad(15), ioff(40002)]
    int* ioff   = zbase + 16;
    int* cursor = ioff + 2 * (NN + 1) + 62;
    int* esrc   = cursor + 2 * NN;

    // conv also zeroes donecnt+ioff (runs before hist in stream order) and
    // sniffs dtype inline -> no memset node, no sniff node.
    conv_kernel<<<157, 256, 0, stream>>>(d_in[8], d_in[9], d_in[10], d_in[11], d_in[12], d_in[13],
                                         d_in[14], d_in[15], d_in[16], d_in[17], d_in[18], d_in[19],
                                         P, PB, zbase);
    hist_kernel<<<(2 * EE) / 256, 256, 0, stream>>>(adj0, adj1, ioff);
    scan_kernel<<<2, 1024, 0, stream>>>(ioff, cursor);
    scatter_kernel<<<(2 * EE) / 256, 256, 0, stream>>>(adj0, adj1, cursor, esrc);
    projm_kernel<<<(2 * NN) / 64, 256, 0, stream>>>(d_in[7], (const int*)d_in[0],
                                                    (const int*)d_in[1], P, PB, h0, probe);

    u16* hcur = h0;
    u16* hnext = h1;
    for (int l = 0; l < 2; ++l) {
        for (int t = 0; t < 3; ++t) {
            fstep_kernel<<<1256, 256, 0, stream>>>(hcur, hnext, ioff, esrc, P, PB, l);
            u16* tmp = hcur; hcur = hnext; hnext = tmp;
        }
    }
    // 6 steps -> final state back in h0 (== hcur)

    cls_kernel<<<BB / 4, 256, 0, stream>>>(hcur, prop0, prop1, labels, P, d_out,
                                           partial, probe);
    loss_kernel<<<1, 256, 0, stream>>>(partial, d_out, probe);
}

// Round 8
// 380.231 us; speedup vs baseline: 1.1836x; 1.0159x over previous
//
#include <hip/hip_runtime.h>
#include <hip/hip_bf16.h>

typedef unsigned short u16;
typedef __attribute__((ext_vector_type(8))) short s16x8;   // 8 bf16 MFMA A/B frag
typedef __attribute__((ext_vector_type(4))) float f32x4;   // MFMA C/D frag

#define NN 20000
#define HH 64
#define EMBD 300
#define EE 160000
#define BB 4096
#define NODES 40000

// f32 param block offsets (floats) in workspace (after 16-float header)
#define OFF_PROJB 0
#define OFF_MSGB  64
#define OFF_BIH   192
#define OFF_BHH   576
#define OFF_CW1T  960
#define OFF_CB1   3008
#define OFF_CW2   3024
#define OFF_CB2   3040
#define PARAM_SZ  3072

// bf16 frag-swizzled weight blocks (u16 units). Each "frag" = 512 u16 = one
// 16(row)x32(k) B-tile stored so lane L reads its 8 elements at frag*512+L*8.
#define PB_WIH   0        // 2 l x 24 frags (jt 0..11, kt 0..1)
#define PB_WHH   24576
#define PB_WMT   49152    // 2 l x 8 frags (jt 0..3, kt 0..1)
#define PB_PROJT 57344    // 40 frags (frag = jt*10+kt, jt 0..3, kt 0..9)
#define PB_SZ    77824

// projm LDS A-tile row stride (u16): 344 -> 172 dwords, <=2-way bank alias (free)
#define APAD 344

// zero region: donecnt(1) + pad(15) + ioff(2*(NN+1))
#define ZCNT (16 + 2 * (NN + 1))

__device__ __forceinline__ float b2f(u16 u) {
    union { unsigned int i; float f; } v; v.i = ((unsigned int)u) << 16; return v.f;
}
__device__ __forceinline__ u16 f2b(float f) {
    union { float f; unsigned int u; } v; v.f = f;
    unsigned int u = v.u;
    return (u16)((u + 0x7FFFu + ((u >> 16) & 1u)) >> 16);   // RNE
}
__device__ __forceinline__ float ldf(const void* p, long long i, int isbf) {
    return isbf ? b2f(((const u16*)p)[i]) : ((const float*)p)[i];
}
__device__ __forceinline__ u16 ldb(const void* p, long long i, int isbf) {
    return isbf ? ((const u16*)p)[i] : f2b(((const float*)p)[i]);
}
__device__ __forceinline__ void stf(void* p, long long i, int isbf, float v) {
    if (isbf) ((u16*)p)[i] = f2b(v);
    else      ((float*)p)[i] = v;
}

// in-kernel dtype sniff: wave-uniform, same decision rule as the old sniff
// kernel (64 samples probe[0,2,..,126]; bf16 iff >=48 have exp in [105,127]).
__device__ __forceinline__ int sniff_inline(const u16* probe, int tid)
{
    u16 x = probe[2 * (tid & 63)];
    unsigned int e = (x >> 7) & 0xFF;
    unsigned long long m = __ballot(e >= 105 && e <= 127);
    return (__popcll(m) >= 48) ? 1 : 0;
}

// ---------------- param convert + frag swizzle (+ zeroing, + sniff) ----------
__global__ __launch_bounds__(256) void conv_kernel(
    const void* projW, const void* projb, const void* msgW, const void* msgb,
    const void* wih, const void* whh, const void* bih, const void* bhh,
    const void* cw1, const void* cb1, const void* cw2, const void* cb2,
    float* P, u16* PB, int* zbase)
{
    int tid = threadIdx.x;
    int isbf = sniff_inline((const u16*)projW, tid);
    int i = blockIdx.x * 256 + tid;

    if (i < ZCNT) zbase[i] = 0;    // donecnt + ioff histogram (hist runs after)

    if (i < 64)    P[OFF_PROJB + i] = ldf(projb, i, isbf);
    if (i < 128)   P[OFF_MSGB + i]  = ldf(msgb, i, isbf);
    if (i < 384)   { P[OFF_BIH + i] = ldf(bih, i, isbf); P[OFF_BHH + i] = ldf(bhh, i, isbf); }
    if (i < 2048)  { int t = i >> 7, k = i & 127; P[OFF_CW1T + i] = ldf(cw1, (long long)k * 16 + t, isbf); }
    if (i < 16)    { P[OFF_CB1 + i] = ldf(cb1, i, isbf); P[OFF_CW2 + i] = ldf(cw2, i, isbf); }
    if (i == 0)    P[OFF_CB2] = ldf(cb2, 0, isbf);

    if (i < 24576) {   // Wih/Whh swizzle: per-l 24 frags
        int l = i / 12288, r = i - l * 12288;
        int frag = r >> 9, rr = r & 511, lane = rr >> 3, e = rr & 7;
        int jt = frag >> 1, kt = frag & 1;
        int srow = jt * 16 + (lane & 15);
        int sk = kt * 32 + ((lane >> 4) << 3) + e;
        long long si = (long long)l * 12288 + srow * 64 + sk;
        PB[PB_WIH + i] = ldb(wih, si, isbf);
        PB[PB_WHH + i] = ldb(whh, si, isbf);
    }
    if (i < 8192) {    // msgW^T swizzle
        int l = i >> 12, r = i & 4095;
        int frag = r >> 9, rr = r & 511, lane = rr >> 3, e = rr & 7;
        int jt = frag >> 1, kt = frag & 1;
        int srow = jt * 16 + (lane & 15);
        int sk = kt * 32 + ((lane >> 4) << 3) + e;
        PB[PB_WMT + i] = ldb(msgW, (long long)l * 4096 + sk * 64 + srow, isbf);
    }
    if (i < 20480) {   // projW^T swizzle, k zero-padded >=300
        int frag = i >> 9, rr = i & 511, lane = rr >> 3, e = rr & 7;
        int jt = frag / 10, kt = frag - jt * 10;
        int srow = jt * 16 + (lane & 15);
        int sk = kt * 32 + ((lane >> 4) << 3) + e;
        PB[PB_PROJT + i] = (sk < 300) ? ldb(projW, (long long)sk * 64 + srow, isbf) : (u16)0;
    }
}

// ---------------- CSR build ----------------
__global__ __launch_bounds__(256) void hist_kernel(const int* __restrict__ adj0,
                                                   const int* __restrict__ adj1, int* off)
{
    int e = blockIdx.x * 256 + threadIdx.x;
    if (e >= 2 * EE) return;
    int b = e / EE, le = e - b * EE;
    const int* adj = b ? adj1 : adj0;
    int tgt = adj[2 * le + 1];
    atomicAdd(&off[b * (NN + 1) + tgt + 1], 1);
}

// scan v2: per-thread contiguous 20-element segment (coalesced loads), local
// register scan, one wave-scan + one 16-wide scan -> 2 block barriers total.
__global__ __launch_bounds__(1024) void scan_kernel(int* off, int* cursor)
{
    int b = blockIdx.x;
    int* o = off + (size_t)b * (NN + 1);
    int* cur = cursor + (size_t)b * NN;
    __shared__ int wsum[16];
    __shared__ int woff_s[16];
    int tid = threadIdx.x, wv = tid >> 6, lane = tid & 63;

    int base = tid * 20;
    int v[20];                 // local inclusive prefix
    int tot = 0;
    #pragma unroll
    for (int k = 0; k < 20; ++k) {
        int i = base + k;
        int x = (i < NN) ? o[i + 1] : 0;
        tot += x;
        v[k] = tot;
    }
    // wave inclusive scan of per-thread totals
    int incl = tot;
    #pragma unroll
    for (int d = 1; d < 64; d <<= 1) {
        int t = __shfl_up(incl, d);
        if (lane >= d) incl += t;
    }
    if (lane == 63) wsum[wv] = incl;
    int lane_excl = incl - tot;
    __syncthreads();           // also orders: all o[] reads before writes below
    if (tid < 16) {
        int w = wsum[tid];
        int s = w;
        #pragma unroll
        for (int d = 1; d < 16; d <<= 1) {
            int t = __shfl_up(s, d, 16);
            if (tid >= d) s += t;
        }
        woff_s[tid] = s - w;   // exclusive wave offset
    }
    __syncthreads();
    int pexcl = woff_s[wv] + lane_excl;
    int run = pexcl;
    #pragma unroll
    for (int k = 0; k < 20; ++k) {
        int i = base + k;
        if (i < NN) { o[i] = run; cur[i] = run; }
        run = pexcl + v[k];
    }
    if (tid == 1023) o[NN] = pexcl;   // base>=NN -> pexcl == grand total
}

__global__ __launch_bounds__(256) void scatter_kernel(const int* __restrict__ adj0,
                                                      const int* __restrict__ adj1,
                                                      int* cursor, int* esrc)
{
    int e = blockIdx.x * 256 + threadIdx.x;
    if (e >= 2 * EE) return;
    int b = e / EE, le = e - b * EE;
    const int* adj = b ? adj1 : adj0;
    int src = adj[2 * le + 0];
    int tgt = adj[2 * le + 1];
    int pos = atomicAdd(&cursor[b * NN + tgt], 1);
    esrc[(size_t)b * EE + pos] = src;
}

// ---------------- embedding gather + projection (MFMA), flat h output -------
// Staging: 8 lanes/row (wave-private rows), uint4 chunks when the 600-B row is
// 16-B aligned (even idx) -> 38 requests/row in 128-B coalesced runs.
__global__ __launch_bounds__(256) void projm_kernel(const void* emb,
                                                    const int* __restrict__ i0,
                                                    const int* __restrict__ i1,
                                                    const float* __restrict__ P,
                                                    const u16* __restrict__ PB,
                                                    u16* __restrict__ h,
                                                    const u16* __restrict__ probe)
{
    __shared__ u16 sA[64 * APAD];
    int tid = threadIdx.x;
    int isbf = sniff_inline(probe, tid);
    int node0 = blockIdx.x * 64;
    int wv = tid >> 6, lane = tid & 63;

    {
        int oct = lane & 7;
        int rbase = wv * 16 + (lane >> 3);     // wave-private rows
        #pragma unroll
        for (int rr = 0; rr < 2; ++rr) {
            int r = rbase + rr * 8;
            int n = node0 + r;
            int bb2 = n >= NN;
            int ln = n - bb2 * NN;
            int idx = bb2 ? i1[ln] : i0[ln];
            u16* dst = sA + r * APAD;
            if (isbf) {
                const u16* src = (const u16*)emb + (size_t)idx * EMBD;
                if ((idx & 1) == 0) {
                    // 16-B aligned row: 37 x uint4 + 8-B tail
                    for (int c = oct; c < 37; c += 8)
                        *(uint4*)(dst + c * 8) = *(const uint4*)(src + c * 8);
                    if (oct == 7)
                        *(uint2*)(dst + 296) = *(const uint2*)(src + 296);
                } else {
                    // 8-B aligned row: 75 x uint2
                    for (int c = oct; c < 75; c += 8)
                        *(uint2*)(dst + c * 4) = *(const uint2*)(src + c * 4);
                }
                if (oct == 0) {
                    ushort4 z = {0, 0, 0, 0};
                    ushort4* d4 = (ushort4*)dst;
                    #pragma unroll
                    for (int c = 75; c < 80; ++c) d4[c] = z;
                }
            } else {
                // f32 path: 75 x float4 (16-B aligned: 1200-B rows)
                const float4* src = (const float4*)((const float*)emb + (size_t)idx * EMBD);
                for (int c = oct; c < 75; c += 8) {
                    float4 f = src[c];
                    ushort4 o4 = { f2b(f.x), f2b(f.y), f2b(f.z), f2b(f.w) };
                    *(ushort4*)(dst + c * 4) = o4;
                }
                if (oct == 0) {
                    ushort4 z = {0, 0, 0, 0};
                    ushort4* d4 = (ushort4*)dst;
                    #pragma unroll
                    for (int c = 75; c < 80; ++c) d4[c] = z;
                }
            }
        }
    }

    int quad = lane >> 4, cn = lane & 15;
    int m0 = wv * 16;
    f32x4 acc[4];
    #pragma unroll
    for (int j = 0; j < 4; ++j) {
        float bb = P[OFF_PROJB + j * 16 + cn];
        acc[j] = {bb, bb, bb, bb};
    }
    #pragma unroll
    for (int kt = 0; kt < 10; ++kt) {
        s16x8 a = *(const s16x8*)&sA[(m0 + cn) * APAD + kt * 32 + quad * 8];
        #pragma unroll
        for (int j = 0; j < 4; ++j) {
            s16x8 bfr = *(const s16x8*)&PB[PB_PROJT + (j * 10 + kt) * 512 + lane * 8];
            acc[j] = __builtin_amdgcn_mfma_f32_16x16x32_bf16(a, bfr, acc[j], 0, 0, 0);
        }
    }
    #pragma unroll
    for (int j = 0; j < 4; ++j)
        #pragma unroll
        for (int r = 0; r < 4; ++r)
            h[(size_t)(node0 + m0 + quad * 4 + r) * 64 + j * 16 + cn] = f2b(acc[j][r]);
}

// ---------------- fused gather + GRU step (v2: 16-node tiles) ----------------
// R3 counters showed the gather is LATENCY-bound (VALUBusy 6%, HBM 18%); R7's
// 1256-block grid was grid-limited at ~4.9 blocks/CU (61% occupancy). v2
// halves the tile: 2504 blocks x 16 nodes -> up to 6+ blocks/CU resident
// (launch_bounds(256,6) caps VGPR at 85 so 24 waves/CU fit).
// Gather: 16 lanes/team, uint2 (4 feats) each, 16-edge chunks, 16 loads in
// flight. Per-feature accumulation is STILL one sequential f32 chain in CSR
// edge order -> bitwise identical to the 8-lane version.
// GRU: 16x64 tile, 4 waves = 4 col-tiles (jt = wave id), 3 barriers.
__global__ __launch_bounds__(256, 6) void fstep_kernel(const u16* __restrict__ h_old,
                                                       u16* __restrict__ h_new,
                                                       const int* __restrict__ ioff,
                                                       const int* __restrict__ esrc,
                                                       const float* __restrict__ P,
                                                       const u16* __restrict__ PB, int l)
{
    __shared__ u16 s_S[16 * 64];
    __shared__ u16 s_h[16 * 64];
    __shared__ u16 s_inc[16 * 64];
    __shared__ float s_deg[16];

    int tid = threadIdx.x;
    int bsw = blockIdx.x;
    int half = (bsw >> 2) & 1;                 // (b&7)>>2 : XCD group -> branch
    int t = (bsw >> 3) * 4 + (bsw & 3);        // tile within branch
    if (t >= 1250) return;                      // uniform over block
    int node0 = half * NN + t * 16;

    // ---------------- phase A: gather ----------------
    {
        int team = tid >> 4, oct = tid & 15;   // 16 teams x 16 lanes
        int node = node0 + team;
        int br = node >= NN;
        int ln = node - br * NN;
        const int* o = ioff + (size_t)br * (NN + 1);
        int s0 = o[ln], s1 = o[ln + 1];
        const int* es = esrc + (size_t)br * EE;
        const u16* hb = h_old + (size_t)br * NN * 64;

        // own row + degree first: overlaps the index-load latency below
        *(uint2*)&s_h[team * 64 + oct * 4] =
            *(const uint2*)&h_old[(size_t)node * 64 + oct * 4];
        if (oct == 0) s_deg[team] = (float)(s1 - s0);

        float acc[4];
        #pragma unroll
        for (int k = 0; k < 4; ++k) acc[k] = 0.f;

        int base = s0, rem = s1 - s0;
        while (rem > 0) {
            int cnt = rem < 16 ? rem : 16;
            int myidx = es[base + (oct < cnt ? oct : cnt - 1)];
            #pragma unroll
            for (int j = 0; j < 16; ++j) {
                int e = __shfl(myidx, j, 16);           // dup of last edge when j>=cnt
                uint2 v = *(const uint2*)&hb[(size_t)e * 64 + oct * 4];
                float w = (j < cnt) ? 1.f : 0.f;
                #pragma unroll
                for (int p = 0; p < 2; ++p) {
                    unsigned int u = (p == 0) ? v.x : v.y;
                    union { unsigned int i; float f; } lo, hi;
                    lo.i = u << 16; hi.i = u & 0xffff0000u;
                    acc[2 * p]     += w * lo.f;
                    acc[2 * p + 1] += w * hi.f;
                }
            }
            base += cnt;
            rem -= cnt;
        }

        u16 pk[4];
        #pragma unroll
        for (int k = 0; k < 4; ++k) pk[k] = f2b(acc[k]);
        *(uint2*)&s_S[team * 64 + oct * 4] = *(const uint2*)pk;
    }
    __syncthreads();   // (1) S/h/deg staged

    // ---------------- phase B: GRU (wave wv owns col-tile jt = wv) ----------
    int wv = tid >> 6, lane = tid & 63;
    int jt = wv;
    int quad = lane >> 4, cn = lane & 15;
    int arow = cn * 64 + quad * 8;
    int fl = lane * 8;

    s16x8 aS0 = *(const s16x8*)&s_S[arow];
    s16x8 aS1 = *(const s16x8*)&s_S[arow + 32];
    s16x8 aH0 = *(const s16x8*)&s_h[arow];
    s16x8 aH1 = *(const s16x8*)&s_h[arow + 32];

    // phase 1: inc = S @ msgW + deg*msgb -> s_inc (no overwrite hazard)
    const u16* WM = PB + PB_WMT + (size_t)l * 4096;
    {
        float mb = P[OFF_MSGB + l * 64 + jt * 16 + cn];
        f32x4 acc;
        acc[0] = s_deg[quad * 4 + 0] * mb;
        acc[1] = s_deg[quad * 4 + 1] * mb;
        acc[2] = s_deg[quad * 4 + 2] * mb;
        acc[3] = s_deg[quad * 4 + 3] * mb;
        acc = __builtin_amdgcn_mfma_f32_16x16x32_bf16(aS0, *(const s16x8*)&WM[(jt * 2 + 0) * 512 + fl], acc, 0, 0, 0);
        acc = __builtin_amdgcn_mfma_f32_16x16x32_bf16(aS1, *(const s16x8*)&WM[(jt * 2 + 1) * 512 + fl], acc, 0, 0, 0);
        #pragma unroll
        for (int r = 0; r < 4; ++r)
            s_inc[(quad * 4 + r) * 64 + jt * 16 + cn] = f2b(acc[r]);
    }
    __syncthreads();   // (2) full inc rows ready

    s16x8 aI0 = *(const s16x8*)&s_inc[arow];
    s16x8 aI1 = *(const s16x8*)&s_inc[arow + 32];
    const u16* WI = PB + PB_WIH + (size_t)l * 12288;
    const u16* WH = PB + PB_WHH + (size_t)l * 12288;
    const float* bi = P + OFF_BIH + l * 192;
    const float* bh = P + OFF_BHH + l * 192;

    {
        int j0 = jt * 16;
        float vr = bi[j0 + cn], vz = bi[64 + j0 + cn], vn = bi[128 + j0 + cn];
        float wr_ = bh[j0 + cn], wz = bh[64 + j0 + cn], wn = bh[128 + j0 + cn];
        f32x4 gr = {vr, vr, vr, vr}, gz = {vz, vz, vz, vz}, gn = {vn, vn, vn, vn};
        f32x4 hr = {wr_, wr_, wr_, wr_}, hz = {wz, wz, wz, wz}, hn = {wn, wn, wn, wn};
        int fr = (jt * 2) * 512 + fl, frz = ((4 + jt) * 2) * 512 + fl, frn = ((8 + jt) * 2) * 512 + fl;
        gr = __builtin_amdgcn_mfma_f32_16x16x32_bf16(aI0, *(const s16x8*)&WI[fr], gr, 0, 0, 0);
        gr = __builtin_amdgcn_mfma_f32_16x16x32_bf16(aI1, *(const s16x8*)&WI[fr + 512], gr, 0, 0, 0);
        gz = __builtin_amdgcn_mfma_f32_16x16x32_bf16(aI0, *(const s16x8*)&WI[frz], gz, 0, 0, 0);
        gz = __builtin_amdgcn_mfma_f32_16x16x32_bf16(aI1, *(const s16x8*)&WI[frz + 512], gz, 0, 0, 0);
        gn = __builtin_amdgcn_mfma_f32_16x16x32_bf16(aI0, *(const s16x8*)&WI[frn], gn, 0, 0, 0);
        gn = __builtin_amdgcn_mfma_f32_16x16x32_bf16(aI1, *(const s16x8*)&WI[frn + 512], gn, 0, 0, 0);
        hr = __builtin_amdgcn_mfma_f32_16x16x32_bf16(aH0, *(const s16x8*)&WH[fr], hr, 0, 0, 0);
        hr = __builtin_amdgcn_mfma_f32_16x16x32_bf16(aH1, *(const s16x8*)&WH[fr + 512], hr, 0, 0, 0);
        hz = __builtin_amdgcn_mfma_f32_16x16x32_bf16(aH0, *(const s16x8*)&WH[frz], hz, 0, 0, 0);
        hz = __builtin_amdgcn_mfma_f32_16x16x32_bf16(aH1, *(const s16x8*)&WH[frz + 512], hz, 0, 0, 0);
        hn = __builtin_amdgcn_mfma_f32_16x16x32_bf16(aH0, *(const s16x8*)&WH[frn], hn, 0, 0, 0);
        hn = __builtin_amdgcn_mfma_f32_16x16x32_bf16(aH1, *(const s16x8*)&WH[frn + 512], hn, 0, 0, 0);
        #pragma unroll
        for (int r = 0; r < 4; ++r) {
            int row = quad * 4 + r;
            float rr = 1.f / (1.f + __expf(-(gr[r] + hr[r])));
            float zz = 1.f / (1.f + __expf(-(gz[r] + hz[r])));
            float nn = tanhf(gn[r] + rr * hn[r]);
            float ho = b2f(s_h[row * 64 + j0 + cn]);
            s_S[row * 64 + j0 + cn] = f2b((1.f - zz) * nn + zz * ho);   // s_S dead after frags
        }
    }
    __syncthreads();   // (3) all result tiles staged in s_S

    // vectorized epilogue: full 128-B row stores (16 lanes x 8 B per node row)
    {
        int team = tid >> 4, oct = tid & 15;
        int node = node0 + team;
        *(uint2*)&h_new[(size_t)node * 64 + oct * 4] =
            *(const uint2*)&s_S[team * 64 + oct * 4];
    }
}

// ---------------- classifier: wave-per-sample (flat h reads) ------------------
// (loss stays a separate kernel: fused last-block reduce needs device-scope
// __threadfence = cross-XCD writeback per block -> measured 84.7 us in R5.)
__global__ __launch_bounds__(256) void cls_kernel(const u16* __restrict__ h,
                                                  const int* __restrict__ p0,
                                                  const int* __restrict__ p1,
                                                  const int* __restrict__ labels,
                                                  const float* __restrict__ P,
                                                  void* out, float* partial,
                                                  const u16* __restrict__ probe)
{
    int tid = threadIdx.x;
    int isbf = sniff_inline(probe, tid);
    int wv = tid >> 6, lane = tid & 63;
    int s = blockIdx.x * 4 + wv;               // 1024 blocks x 4 waves = 4096
    int n0 = p0[s], n1 = p1[s];
    float f0 = b2f(h[(size_t)n0 * 64 + lane]);
    float f1 = b2f(h[(size_t)(NN + n1) * 64 + lane]);
    float z = P[OFF_CB2];
    #pragma unroll
    for (int t = 0; t < 16; ++t) {
        float part = f0 * P[OFF_CW1T + t * 128 + lane] + f1 * P[OFF_CW1T + t * 128 + 64 + lane];
        #pragma unroll
        for (int off = 32; off; off >>= 1) part += __shfl_xor(part, off);
        z += fmaxf(part + P[OFF_CB1 + t], 0.f) * P[OFF_CW2 + t];
    }
    float p = 1.f / (1.f + expf(-z));
    float y = (float)labels[s];
    const float eps = 1e-7f;
    float pc  = fminf(fmaxf(p, eps), 1.f);
    float pc1 = fminf(fmaxf(1.f - p, eps), 1.f);
    float term = y * logf(pc) + (1.f - y) * logf(pc1);
    __shared__ float red[4];
    if (lane == 0) { stf(out, s, isbf, p); red[wv] = term; }
    __syncthreads();
    if (tid == 0) partial[blockIdx.x] = red[0] + red[1] + red[2] + red[3];
}

__global__ __launch_bounds__(256) void loss_kernel(const float* __restrict__ partial,
                                                   void* out, const u16* __restrict__ probe)
{
    int tid = threadIdx.x;
    int isbf = sniff_inline(probe, tid);
    __shared__ float red[256];
    float s = 0.f;
    for (int i = tid; i < 1024; i += 256) s += partial[i];
    red[tid] = s;
    __syncthreads();
    for (int d = 128; d > 0; d >>= 1) {
        if (tid < d) red[tid] += red[tid + d];
        __syncthreads();
    }
    if (tid == 0) stf(out, BB, isbf, -red[0] / (float)BB);
}

extern "C" void kernel_launch(void* const* d_in, const int* in_sizes, int n_in,
                              void* d_out, int out_size, void* d_ws, size_t ws_size,
                              hipStream_t stream)
{
    const int* adj0   = (const int*)d_in[2];
    const int* adj1   = (const int*)d_in[3];
    const int* prop0  = (const int*)d_in[4];
    const int* prop1  = (const int*)d_in[5];
    const int* labels = (const int*)d_in[6];
    const u16* probe  = (const u16*)d_in[8];   // proj_W doubles as dtype probe

    float* P  = (float*)d_ws + 16;
    u16* PB   = (u16*)(P + PARAM_SZ);
    // h rows are 128 B; align h0 to 256 B so every row is exactly one cache line
    u16* h0   = (u16*)(((uintptr_t)(PB + PB_SZ) + 255) & ~(uintptr_t)255);
    u16* h1   = h0 + (size_t)NODES * 64;
    float* partial = (float*)(h1 + (size_t)NODES * 64);
    int* zbase  = (int*)(partial + 1024);      // [donecnt(1), pad(15), ioff(40002)]
    int* ioff   = zbase + 16;
    int* cursor = ioff + 2 * (NN + 1) + 62;
    int* esrc   = cursor + 2 * NN;

    // conv also zeroes donecnt+ioff (runs before hist in stream order) and
    // sniffs dtype inline -> no memset node, no sniff node.
    conv_kernel<<<157, 256, 0, stream>>>(d_in[8], d_in[9], d_in[10], d_in[11], d_in[12], d_in[13],
                                         d_in[14], d_in[15], d_in[16], d_in[17], d_in[18], d_in[19],
                                         P, PB, zbase);
    hist_kernel<<<(2 * EE) / 256, 256, 0, stream>>>(adj0, adj1, ioff);
    scan_kernel<<<2, 1024, 0, stream>>>(ioff, cursor);
    scatter_kernel<<<(2 * EE) / 256, 256, 0, stream>>>(adj0, adj1, cursor, esrc);
    projm_kernel<<<(2 * NN) / 64, 256, 0, stream>>>(d_in[7], (const int*)d_in[0],
                                                    (const int*)d_in[1], P, PB, h0, probe);

    u16* hcur = h0;
    u16* hnext = h1;
    for (int l = 0; l < 2; ++l) {
        for (int t = 0; t < 3; ++t) {
            fstep_kernel<<<2504, 256, 0, stream>>>(hcur, hnext, ioff, esrc, P, PB, l);
            u16* tmp = hcur; hcur = hnext; hnext = tmp;
        }
    }
    // 6 steps -> final state back in h0 (== hcur)

    cls_kernel<<<BB / 4, 256, 0, stream>>>(hcur, prop0, prop1, labels, P, d_out,
                                           partial, probe);
    loss_kernel<<<1, 256, 0, stream>>>(partial, d_out, probe);
}